// Round 1
// baseline (662.748 us; speedup 1.0000x reference)
//
#include <hip/hip_runtime.h>
#include <math.h>

// Problem constants
constexpr int N = 8, C = 128, H = 64, W = 64;
constexpr int PIX = H * W;            // 4096
constexpr int KK = 49;                // 7x7 window

// ws layout in floats
constexpr size_t WT_OFF  = 0;                       // 3*128*128 = 49152 floats
constexpr size_t Y_OFF   = 65536;                   // aligned; y1,y2,y3 follow
constexpr size_t YSZ     = (size_t)N * C * PIX;     // 4,194,304 floats each
constexpr size_t ATT_OFF = Y_OFF + 3 * YSZ;         // attn: N*H*49*W floats

// ---------------------------------------------------------------------------
// K0: transpose the three 128x128 weights: Wt[k][o] = W[o][k]
// ---------------------------------------------------------------------------
__global__ void transpose_w(const float* __restrict__ w1,
                            const float* __restrict__ w2,
                            const float* __restrict__ w3,
                            float* __restrict__ wt) {
    int ws = blockIdx.x;
    const float* src = (ws == 0) ? w1 : (ws == 1) ? w2 : w3;
    float* dst = wt + (size_t)ws * 16384;
    for (int idx = threadIdx.x; idx < 16384; idx += blockDim.x) {
        int o = idx & 127;
        int c = idx >> 7;
        dst[idx] = src[o * 128 + c];   // dst[c*128+o] coalesced write
    }
}

// ---------------------------------------------------------------------------
// K1: fused 3x conv1x1 GEMM. Block: one (wsel, n, pixel-tile of 128).
// C[128 oc][128 px] = W[128][128] * X[128][128], K chunked by 64 in LDS.
// ---------------------------------------------------------------------------
#define LP 136   // padded LDS row stride (floats), 16B-aligned, breaks pow2

__global__ __launch_bounds__(256) void conv3(const float* __restrict__ x,
                                             const float* __restrict__ wt,
                                             float* __restrict__ y) {
    __shared__ float la[64 * LP];
    __shared__ float lb[64 * LP];

    int bid  = blockIdx.x;
    int wsel = bid % 3;
    int t    = bid / 3;
    int pt   = t & 31;
    int n    = t >> 5;
    int p0   = pt * 128;

    const float* Wm = wt + (size_t)wsel * 16384;          // Wt[k][o]
    const float* X  = x + (size_t)n * C * PIX;            // X[c][p]
    float*       Y  = y + (size_t)wsel * YSZ + (size_t)n * C * PIX;

    int tid = threadIdx.x;
    int tx  = tid & 15, ty = tid >> 4;
    int o0  = ty * 8, px0 = tx * 8;

    float acc[8][8];
#pragma unroll
    for (int i = 0; i < 8; i++)
#pragma unroll
        for (int j = 0; j < 8; j++) acc[i][j] = 0.f;

    for (int kk = 0; kk < 128; kk += 64) {
        // stage A (weights, [k][o]) and B (acts, [k][px]) chunks
#pragma unroll
        for (int i = 0; i < 8; i++) {
            int idx = tid + i * 256;
            int row = idx >> 5;
            int c4  = (idx & 31) * 4;
            *(float4*)&la[row * LP + c4] =
                *(const float4*)&Wm[(size_t)(kk + row) * 128 + c4];
            *(float4*)&lb[row * LP + c4] =
                *(const float4*)&X[(size_t)(kk + row) * PIX + p0 + c4];
        }
        __syncthreads();

#pragma unroll 4
        for (int k = 0; k < 64; k++) {
            float4 a0 = *(float4*)&la[k * LP + o0];
            float4 a1 = *(float4*)&la[k * LP + o0 + 4];
            float4 b0 = *(float4*)&lb[k * LP + px0];
            float4 b1 = *(float4*)&lb[k * LP + px0 + 4];
            float a[8] = {a0.x, a0.y, a0.z, a0.w, a1.x, a1.y, a1.z, a1.w};
            float b[8] = {b0.x, b0.y, b0.z, b0.w, b1.x, b1.y, b1.z, b1.w};
#pragma unroll
            for (int i = 0; i < 8; i++)
#pragma unroll
                for (int j = 0; j < 8; j++)
                    acc[i][j] = fmaf(a[i], b[j], acc[i][j]);
        }
        __syncthreads();
    }

#pragma unroll
    for (int i = 0; i < 8; i++) {
#pragma unroll
        for (int j2 = 0; j2 < 2; j2++) {
            float4 v = make_float4(acc[i][j2 * 4 + 0], acc[i][j2 * 4 + 1],
                                   acc[i][j2 * 4 + 2], acc[i][j2 * 4 + 3]);
            *(float4*)&Y[(size_t)(o0 + i) * PIX + p0 + px0 + j2 * 4] = v;
        }
    }
}

// ---------------------------------------------------------------------------
// K2: sim = x1 . win(x2), softmax over 49 -> attn[n][h][k][w]
// Block: (n, row-pair). 4 waves = 2 rows x 2 c-halves. lane = column w.
// Zero-padded OOB entries contribute sim=0 and DO participate in softmax
// (matches reference's zero-pad + unmasked softmax).
// ---------------------------------------------------------------------------
__global__ __launch_bounds__(256) void simsoft(const float* __restrict__ ybase,
                                               float* __restrict__ attn) {
    __shared__ float red[2][KK][64];

    int bid = blockIdx.x;
    int hp  = bid & 31;
    int n   = bid >> 5;

    int tid = threadIdx.x;
    int wid = tid >> 6;
    int w   = tid & 63;
    int r   = wid & 1;
    int ch  = wid >> 1;
    int h   = hp * 2 + r;
    int cb  = ch * 64;

    const float* x1 = ybase + (size_t)n * C * PIX;           // y1
    const float* x2 = ybase + YSZ + (size_t)n * C * PIX;     // y2

    float acc[KK];
#pragma unroll
    for (int k = 0; k < KK; k++) acc[k] = 0.f;

    for (int c = 0; c < 64; c++) {
        int cc = cb + c;
        float a = x1[(size_t)cc * PIX + h * 64 + w];
        const float* x2c = x2 + (size_t)cc * PIX;
#pragma unroll
        for (int k = 0; k < KK; k++) {
            int di = k / 7 - 3;
            int dj = k % 7 - 3;
            int hh = h + di;                  // wave-uniform
            if ((unsigned)hh < 64u) {
                int ww = w + dj;
                float v = ((unsigned)ww < 64u) ? x2c[hh * 64 + ww] : 0.f;
                acc[k] = fmaf(a, v, acc[k]);
            }
        }
    }

    if (ch == 1) {
#pragma unroll
        for (int k = 0; k < KK; k++) red[r][k][w] = acc[k];
    }
    __syncthreads();
    if (ch == 0) {
#pragma unroll
        for (int k = 0; k < KK; k++) acc[k] += red[r][k][w];
        // softmax over 49 (includes zeros for fully-OOB window slots)
        float m = acc[0];
#pragma unroll
        for (int k = 1; k < KK; k++) m = fmaxf(m, acc[k]);
        float s = 0.f;
#pragma unroll
        for (int k = 0; k < KK; k++) {
            float e = __expf(acc[k] - m);
            acc[k] = e;
            s += e;
        }
        float inv = 1.f / s;
        float* ap = attn + ((size_t)(n * 64 + h) * KK) * 64 + w;
#pragma unroll
        for (int k = 0; k < KK; k++) ap[(size_t)k * 64] = acc[k] * inv;
    }
}

// ---------------------------------------------------------------------------
// K3: out[n][c][h][w] = sum_k attn[n][h][k][w] * x3[n][c][h+di][w+dj]
// Block: (n, h). 4 waves = 4 c-quarters. lane = column w.
// ---------------------------------------------------------------------------
__global__ __launch_bounds__(256) void pv(const float* __restrict__ ybase,
                                          const float* __restrict__ attn,
                                          float* __restrict__ out) {
    int bid = blockIdx.x;
    int h   = bid & 63;
    int n   = bid >> 6;

    int tid = threadIdx.x;
    int wid = tid >> 6;
    int w   = tid & 63;
    int cb  = wid * 32;

    const float* x3 = ybase + 2 * YSZ + (size_t)n * C * PIX;
    const float* ap = attn + (size_t)(n * 64 + h) * KK * 64 + w;

    float ar[KK];
#pragma unroll
    for (int k = 0; k < KK; k++) ar[k] = ap[(size_t)k * 64];

    for (int c = 0; c < 32; c++) {
        int cc = cb + c;
        const float* x3c = x3 + (size_t)cc * PIX;
        float acc = 0.f;
#pragma unroll
        for (int k = 0; k < KK; k++) {
            int di = k / 7 - 3;
            int dj = k % 7 - 3;
            int hh = h + di;                 // wave-uniform
            if ((unsigned)hh < 64u) {
                int ww = w + dj;
                float v = ((unsigned)ww < 64u) ? x3c[hh * 64 + ww] : 0.f;
                acc = fmaf(ar[k], v, acc);
            }
        }
        out[(size_t)(n * C + cc) * PIX + h * 64 + w] = acc;
    }
}

// ---------------------------------------------------------------------------
extern "C" void kernel_launch(void* const* d_in, const int* in_sizes, int n_in,
                              void* d_out, int out_size, void* d_ws, size_t ws_size,
                              hipStream_t stream) {
    const float* x  = (const float*)d_in[0];
    const float* w1 = (const float*)d_in[1];
    const float* w2 = (const float*)d_in[2];
    const float* w3 = (const float*)d_in[3];
    float* wsf = (float*)d_ws;

    transpose_w<<<3, 256, 0, stream>>>(w1, w2, w3, wsf + WT_OFF);
    conv3<<<768, 256, 0, stream>>>(x, wsf + WT_OFF, wsf + Y_OFF);
    simsoft<<<256, 256, 0, stream>>>(wsf + Y_OFF, wsf + ATT_OFF);
    pv<<<512, 256, 0, stream>>>(wsf + Y_OFF, wsf + ATT_OFF, (float*)d_out);
}

// Round 3
// 134.788 us; speedup vs baseline: 4.9170x; 4.9170x over previous
//
#include <hip/hip_runtime.h>
#include <math.h>

// Problem constants
constexpr int N = 8, C = 128, H = 64, W = 64;
constexpr int PIX = H * W;            // 4096
constexpr int KK = 49;                // 7x7 window

// ws layout in floats
constexpr size_t WT_OFF  = 0;                       // 3*128*128 = 49152 floats
constexpr size_t Y_OFF   = 65536;                   // aligned; y1,y2,y3 follow
constexpr size_t YSZ     = (size_t)N * C * PIX;     // 4,194,304 floats each
constexpr size_t ATT_OFF = Y_OFF + 3 * YSZ;         // attn: N*H*49*W floats

// ---------------------------------------------------------------------------
// K0: transpose the three 128x128 weights: Wt[k][o] = W[o][k]
// ---------------------------------------------------------------------------
__global__ void transpose_w(const float* __restrict__ w1,
                            const float* __restrict__ w2,
                            const float* __restrict__ w3,
                            float* __restrict__ wt) {
    int ws = blockIdx.x;
    const float* src = (ws == 0) ? w1 : (ws == 1) ? w2 : w3;
    float* dst = wt + (size_t)ws * 16384;
    for (int idx = threadIdx.x; idx < 16384; idx += blockDim.x) {
        int o = idx & 127;
        int c = idx >> 7;
        dst[idx] = src[o * 128 + c];   // dst[c*128+o] coalesced write
    }
}

// ---------------------------------------------------------------------------
// K1: fused 3x conv1x1 GEMM. Block: one (wsel, n, pixel-tile of 128).
// C[128 oc][128 px] = W[128][128] * X[128][128], K chunked by 64 in LDS.
// ---------------------------------------------------------------------------
#define LP 136   // padded LDS row stride (floats), 16B-aligned, breaks pow2

__global__ __launch_bounds__(256) void conv3(const float* __restrict__ x,
                                             const float* __restrict__ wt,
                                             float* __restrict__ y) {
    __shared__ float la[64 * LP];
    __shared__ float lb[64 * LP];

    int bid  = blockIdx.x;
    int wsel = bid % 3;
    int t    = bid / 3;
    int pt   = t & 31;
    int n    = t >> 5;
    int p0   = pt * 128;

    const float* Wm = wt + (size_t)wsel * 16384;          // Wt[k][o]
    const float* X  = x + (size_t)n * C * PIX;            // X[c][p]
    float*       Y  = y + (size_t)wsel * YSZ + (size_t)n * C * PIX;

    int tid = threadIdx.x;
    int tx  = tid & 15, ty = tid >> 4;
    int o0  = ty * 8, px0 = tx * 8;

    float acc[8][8];
#pragma unroll
    for (int i = 0; i < 8; i++)
#pragma unroll
        for (int j = 0; j < 8; j++) acc[i][j] = 0.f;

    for (int kk = 0; kk < 128; kk += 64) {
#pragma unroll
        for (int i = 0; i < 8; i++) {
            int idx = tid + i * 256;
            int row = idx >> 5;
            int c4  = (idx & 31) * 4;
            *(float4*)&la[row * LP + c4] =
                *(const float4*)&Wm[(size_t)(kk + row) * 128 + c4];
            *(float4*)&lb[row * LP + c4] =
                *(const float4*)&X[(size_t)(kk + row) * PIX + p0 + c4];
        }
        __syncthreads();

#pragma unroll 4
        for (int k = 0; k < 64; k++) {
            float4 a0 = *(float4*)&la[k * LP + o0];
            float4 a1 = *(float4*)&la[k * LP + o0 + 4];
            float4 b0 = *(float4*)&lb[k * LP + px0];
            float4 b1 = *(float4*)&lb[k * LP + px0 + 4];
            float a[8] = {a0.x, a0.y, a0.z, a0.w, a1.x, a1.y, a1.z, a1.w};
            float b[8] = {b0.x, b0.y, b0.z, b0.w, b1.x, b1.y, b1.z, b1.w};
#pragma unroll
            for (int i = 0; i < 8; i++)
#pragma unroll
                for (int j = 0; j < 8; j++)
                    acc[i][j] = fmaf(a[i], b[j], acc[i][j]);
        }
        __syncthreads();
    }

#pragma unroll
    for (int i = 0; i < 8; i++) {
#pragma unroll
        for (int j2 = 0; j2 < 2; j2++) {
            float4 v = make_float4(acc[i][j2 * 4 + 0], acc[i][j2 * 4 + 1],
                                   acc[i][j2 * 4 + 2], acc[i][j2 * 4 + 3]);
            *(float4*)&Y[(size_t)(o0 + i) * PIX + p0 + px0 + j2 * 4] = v;
        }
    }
}

// ---------------------------------------------------------------------------
// Window-kernel LDS geometry: halo-padded rows, NO bounds masks in the
// inner loop. Staged tile: 8 rows x 16 channels x width 76.
// Col layout: col = 4 + ww for ww in [0,64); cols 0..3 and 68..75 stay zero
// (zeroed once, interior float4 writes only touch cols 4..67).
// ---------------------------------------------------------------------------
constexpr int CCH = 16;   // channels per LDS chunk
constexpr int LW  = 76;   // padded row width (floats); interior at cols 4..67
constexpr int SROWS = 8;  // staged rows: h0-3 .. h0+4

// ---------------------------------------------------------------------------
// K2: sim + softmax -> attn[n][h][k][w]
// Block = (n, row-pair h0=2*hp). 512 thr = 8 waves: (r in {0,1}, cq in {0..3}).
// Wave (r,cq) accumulates 49 sums for row h0+r over channels {chunk + cq*4+i}.
// Cross-cq reduce via LDS (aliased over stage buffer), softmax in-register.
// ---------------------------------------------------------------------------
__global__ __launch_bounds__(512) void simsoft2(const float* __restrict__ ybase,
                                                float* __restrict__ attn) {
    __shared__ float smem[12544];   // max(stage 9728, red 2*2*49*64=12544) floats
    float* s2 = smem;

    int bid = blockIdx.x;
    int hp  = bid & 31;
    int n   = bid >> 5;
    int h0  = hp * 2;

    int tid = threadIdx.x;
    int wid = tid >> 6;
    int w   = tid & 63;
    int r   = wid & 1;
    int cq  = wid >> 1;
    int h   = h0 + r;

    const float* x1 = ybase + (size_t)n * C * PIX;           // y1
    const float* x2 = ybase + YSZ + (size_t)n * C * PIX;     // y2

    // zero stage buffer once (halo columns persist as zero across chunks)
    for (int i = tid; i < SROWS * CCH * LW; i += 512) s2[i] = 0.f;
    __syncthreads();   // RACE FIX: zeros must land before any staging write

    float acc[KK];
#pragma unroll
    for (int k = 0; k < KK; k++) acc[k] = 0.f;

    for (int ch = 0; ch < C; ch += CCH) {
        // stage interior: 8 rows x 16 c x 16 float4 = 2048 f4, 4 per thread
#pragma unroll
        for (int i = 0; i < 4; i++) {
            int q   = tid + i * 512;
            int w4  = q & 15;
            int c   = (q >> 4) & 15;
            int row = q >> 8;             // 0..7
            int hh  = h0 - 3 + row;
            float4 v = make_float4(0.f, 0.f, 0.f, 0.f);
            if ((unsigned)hh < 64u)
                v = *(const float4*)&x2[(size_t)(ch + c) * PIX + hh * 64 + w4 * 4];
            *(float4*)&s2[(row * CCH + c) * LW + 4 + w4 * 4] = v;
        }
        __syncthreads();

#pragma unroll
        for (int i = 0; i < 4; i++) {
            int cl = cq * 4 + i;
            float a = x1[(size_t)(ch + cl) * PIX + h * 64 + w];
#pragma unroll
            for (int k = 0; k < KK; k++) {
                int di = k / 7 - 3;
                int dj = k % 7 - 3;
                int row = r + 3 + di;     // 0..7, always staged
                float v = s2[(row * CCH + cl) * LW + 4 + w + dj];
                acc[k] = fmaf(a, v, acc[k]);
            }
        }
        __syncthreads();
    }

    // cross-cq reduction in LDS (stage buffer is dead now)
    float* red = smem;   // [r][buf][k][w] = [2][2][49][64]
#define RED(rr, bb, kk_) red[(((rr) * 2 + (bb)) * KK + (kk_)) * 64 + w]
    if (cq == 1) {
#pragma unroll
        for (int k = 0; k < KK; k++) RED(r, 0, k) = acc[k];
    }
    if (cq == 3) {
#pragma unroll
        for (int k = 0; k < KK; k++) RED(r, 1, k) = acc[k];
    }
    __syncthreads();
    if (cq == 0) {
#pragma unroll
        for (int k = 0; k < KK; k++) acc[k] += RED(r, 0, k);
    }
    if (cq == 2) {
#pragma unroll
        for (int k = 0; k < KK; k++) acc[k] += RED(r, 1, k);
    }
    __syncthreads();
    if (cq == 2) {
#pragma unroll
        for (int k = 0; k < KK; k++) RED(r, 0, k) = acc[k];
    }
    __syncthreads();
    if (cq == 0) {
#pragma unroll
        for (int k = 0; k < KK; k++) acc[k] += RED(r, 0, k);
        // softmax over 49 (zero-padded OOB slots participate, matching ref)
        float m = acc[0];
#pragma unroll
        for (int k = 1; k < KK; k++) m = fmaxf(m, acc[k]);
        float s = 0.f;
#pragma unroll
        for (int k = 0; k < KK; k++) {
            float e = __expf(acc[k] - m);
            acc[k] = e;
            s += e;
        }
        float inv = 1.f / s;
        float* ap = attn + ((size_t)(n * 64 + h) * KK) * 64 + w;
#pragma unroll
        for (int k = 0; k < KK; k++) ap[(size_t)k * 64] = acc[k] * inv;
    }
#undef RED
}

// ---------------------------------------------------------------------------
// K3: out[c][h][w] = sum_k attn[h][k][w] * x3[c][h+di][w+dj]
// Same block structure as simsoft2; attn held in 49 registers per lane;
// no reduction (channels are independent outputs).
// ---------------------------------------------------------------------------
__global__ __launch_bounds__(512) void pv2(const float* __restrict__ ybase,
                                           const float* __restrict__ attn,
                                           float* __restrict__ out) {
    __shared__ float s3[SROWS * CCH * LW];

    int bid = blockIdx.x;
    int hp  = bid & 31;
    int n   = bid >> 5;
    int h0  = hp * 2;

    int tid = threadIdx.x;
    int wid = tid >> 6;
    int w   = tid & 63;
    int r   = wid & 1;
    int cq  = wid >> 1;
    int h   = h0 + r;

    const float* x3 = ybase + 2 * YSZ + (size_t)n * C * PIX;
    const float* ap = attn + ((size_t)(n * 64 + h) * KK) * 64 + w;

    float ar[KK];
#pragma unroll
    for (int k = 0; k < KK; k++) ar[k] = ap[(size_t)k * 64];

    for (int i = tid; i < SROWS * CCH * LW; i += 512) s3[i] = 0.f;
    __syncthreads();   // RACE FIX: zeros must land before any staging write

    for (int ch = 0; ch < C; ch += CCH) {
#pragma unroll
        for (int i = 0; i < 4; i++) {
            int q   = tid + i * 512;
            int w4  = q & 15;
            int c   = (q >> 4) & 15;
            int row = q >> 8;
            int hh  = h0 - 3 + row;
            float4 v = make_float4(0.f, 0.f, 0.f, 0.f);
            if ((unsigned)hh < 64u)
                v = *(const float4*)&x3[(size_t)(ch + c) * PIX + hh * 64 + w4 * 4];
            *(float4*)&s3[(row * CCH + c) * LW + 4 + w4 * 4] = v;
        }
        __syncthreads();

#pragma unroll
        for (int i = 0; i < 4; i++) {
            int cl = cq * 4 + i;
            int gc = ch + cl;
            float acc = 0.f;
#pragma unroll
            for (int k = 0; k < KK; k++) {
                int di = k / 7 - 3;
                int dj = k % 7 - 3;
                int row = r + 3 + di;
                float v = s3[(row * CCH + cl) * LW + 4 + w + dj];
                acc = fmaf(ar[k], v, acc);
            }
            out[(size_t)(n * C + gc) * PIX + h * 64 + w] = acc;
        }
        __syncthreads();
    }
}

// ---------------------------------------------------------------------------
extern "C" void kernel_launch(void* const* d_in, const int* in_sizes, int n_in,
                              void* d_out, int out_size, void* d_ws, size_t ws_size,
                              hipStream_t stream) {
    const float* x  = (const float*)d_in[0];
    const float* w1 = (const float*)d_in[1];
    const float* w2 = (const float*)d_in[2];
    const float* w3 = (const float*)d_in[3];
    float* wsf = (float*)d_ws;

    transpose_w<<<3, 256, 0, stream>>>(w1, w2, w3, wsf + WT_OFF);
    conv3<<<768, 256, 0, stream>>>(x, wsf + WT_OFF, wsf + Y_OFF);
    simsoft2<<<256, 512, 0, stream>>>(wsf + Y_OFF, wsf + ATT_OFF);
    pv2<<<256, 512, 0, stream>>>(wsf + Y_OFF, wsf + ATT_OFF, (float*)d_out);
}

// Round 4
// 122.500 us; speedup vs baseline: 5.4102x; 1.1003x over previous
//
#include <hip/hip_runtime.h>
#include <math.h>

// Problem constants
constexpr int N = 8, C = 128, H = 64, W = 64;
constexpr int PIX = H * W;            // 4096
constexpr int KK = 49;                // 7x7 window

// ws layout in floats
constexpr size_t M_OFF   = 0;                        // M = W1^T W2, 128x128 (k=a major)
constexpr size_t WT3_OFF = 16384;                    // W3 transposed [k][o]
constexpr size_t Z_OFF   = 65536;                    // z = M^T x, N*C*PIX
constexpr size_t YSZ     = (size_t)N * C * PIX;      // 4,194,304 floats
constexpr size_t ATT_OFF = Z_OFF + YSZ;              // attn: N*H*49*W
constexpr size_t ATTSZ   = (size_t)N * H * KK * W;   // 1,605,632 floats
constexpr size_t U_OFF   = ATT_OFF + ATTSZ;          // u = PV(x), N*C*PIX

// ---------------------------------------------------------------------------
// K0: prep. Blocks 0..63: M[a][b] = sum_c W1[c][a]*W2[c][b]  (2 rows/block).
//     Blocks 64..67: Wt3[c][o] = W3[o][c].
// ---------------------------------------------------------------------------
__global__ __launch_bounds__(256) void prep(const float* __restrict__ w1,
                                            const float* __restrict__ w2,
                                            const float* __restrict__ w3,
                                            float* __restrict__ Mout,
                                            float* __restrict__ wt3) {
    int bid = blockIdx.x, tid = threadIdx.x;
    if (bid < 64) {
        int a = bid * 2 + (tid >> 7);
        int b = tid & 127;
        float s = 0.f;
        for (int c = 0; c < 128; c++)
            s = fmaf(w1[c * 128 + a], w2[c * 128 + b], s);
        Mout[a * 128 + b] = s;
    } else {
        int base = (bid - 64) * 4096;
        for (int i = tid; i < 4096; i += 256) {
            int idx = base + i;
            int o = idx & 127, c = idx >> 7;
            wt3[idx] = w3[o * 128 + c];     // wt3[c*128+o] = w3[o][c]
        }
    }
}

// ---------------------------------------------------------------------------
// K1: generic 1x1-conv GEMM. Block tile: 128 oc x 64 px, K=128 chunked by 32.
// A = [k][o] 128x128 (fp32), Bsrc = [n][c][pix], Yout = [n][oc][pix].
// Grid: 512 = n(8) x px-tile(64). Threads 256 = 16tx x 16ty; thread tile 8x4.
// ---------------------------------------------------------------------------
__global__ __launch_bounds__(256) void convk(const float* __restrict__ A,
                                             const float* __restrict__ Bsrc,
                                             float* __restrict__ Yout) {
    __shared__ float la[32 * 136];   // [k][oc], pad 8
    __shared__ float lb[32 * 72];    // [k][px], pad 8

    int bid = blockIdx.x;
    int pt  = bid & 63;
    int n   = bid >> 6;
    int p0  = pt * 64;

    const float* B = Bsrc + (size_t)n * C * PIX;
    float*       Y = Yout + (size_t)n * C * PIX;

    int tid = threadIdx.x;
    int tx  = tid & 15, ty = tid >> 4;
    int oc0 = ty * 8, px0 = tx * 4;

    float acc[8][4];
#pragma unroll
    for (int i = 0; i < 8; i++)
#pragma unroll
        for (int j = 0; j < 4; j++) acc[i][j] = 0.f;

    for (int kk = 0; kk < 128; kk += 32) {
        // stage A chunk: 32x128 = 1024 f4, 4 per thread
#pragma unroll
        for (int i = 0; i < 4; i++) {
            int q   = tid + i * 256;
            int row = q >> 5;
            int c4  = (q & 31) * 4;
            *(float4*)&la[row * 136 + c4] =
                *(const float4*)&A[(kk + row) * 128 + c4];
        }
        // stage B chunk: 32x64 = 512 f4, 2 per thread
#pragma unroll
        for (int i = 0; i < 2; i++) {
            int q   = tid + i * 256;
            int row = q >> 4;
            int c4  = (q & 15) * 4;
            *(float4*)&lb[row * 72 + c4] =
                *(const float4*)&B[(size_t)(kk + row) * PIX + p0 + c4];
        }
        __syncthreads();

#pragma unroll 8
        for (int k = 0; k < 32; k++) {
            float4 a0 = *(float4*)&la[k * 136 + oc0];
            float4 a1 = *(float4*)&la[k * 136 + oc0 + 4];
            float4 b0 = *(float4*)&lb[k * 72 + px0];
            float a[8] = {a0.x, a0.y, a0.z, a0.w, a1.x, a1.y, a1.z, a1.w};
            float b[4] = {b0.x, b0.y, b0.z, b0.w};
#pragma unroll
            for (int i = 0; i < 8; i++)
#pragma unroll
                for (int j = 0; j < 4; j++)
                    acc[i][j] = fmaf(a[i], b[j], acc[i][j]);
        }
        __syncthreads();
    }

#pragma unroll
    for (int i = 0; i < 8; i++) {
        float4 v = make_float4(acc[i][0], acc[i][1], acc[i][2], acc[i][3]);
        *(float4*)&Y[(size_t)(oc0 + i) * PIX + p0 + px0] = v;
    }
}

// ---------------------------------------------------------------------------
// Window-kernel LDS geometry: halo-padded rows, NO bounds masks inner-loop.
// Staged tile: 8 rows x 16 channels x width 76 (cols 0..3, 68..75 stay zero).
// ---------------------------------------------------------------------------
constexpr int CCH = 16;   // channels per LDS chunk
constexpr int LW  = 76;   // padded row width (floats); interior at cols 4..67
constexpr int SROWS = 8;  // staged rows: h0-3 .. h0+4

// ---------------------------------------------------------------------------
// K2: sim(p,k) = z(p) . x(p+dk), softmax -> attn[n][h][k][w]
// Block = (n, row-pair). 512 thr = 8 waves: (r in {0,1}, cq in {0..3}).
// ---------------------------------------------------------------------------
__global__ __launch_bounds__(512) void simsoft2(const float* __restrict__ z,
                                                const float* __restrict__ x,
                                                float* __restrict__ attn) {
    __shared__ float smem[12544];   // max(stage 9728, red 2*2*49*64=12544)
    float* s2 = smem;

    int bid = blockIdx.x;
    int hp  = bid & 31;
    int n   = bid >> 5;
    int h0  = hp * 2;

    int tid = threadIdx.x;
    int wid = tid >> 6;
    int w   = tid & 63;
    int r   = wid & 1;
    int cq  = wid >> 1;
    int h   = h0 + r;

    const float* zq = z + (size_t)n * C * PIX;     // query vectors
    const float* xk = x + (size_t)n * C * PIX;     // keys = raw x

    for (int i = tid; i < SROWS * CCH * LW; i += 512) s2[i] = 0.f;
    __syncthreads();   // zeros must land before any staging write

    float acc[KK];
#pragma unroll
    for (int k = 0; k < KK; k++) acc[k] = 0.f;

    for (int ch = 0; ch < C; ch += CCH) {
#pragma unroll
        for (int i = 0; i < 4; i++) {
            int q   = tid + i * 512;
            int w4  = q & 15;
            int c   = (q >> 4) & 15;
            int row = q >> 8;             // 0..7
            int hh  = h0 - 3 + row;
            float4 v = make_float4(0.f, 0.f, 0.f, 0.f);
            if ((unsigned)hh < 64u)
                v = *(const float4*)&xk[(size_t)(ch + c) * PIX + hh * 64 + w4 * 4];
            *(float4*)&s2[(row * CCH + c) * LW + 4 + w4 * 4] = v;
        }
        __syncthreads();

#pragma unroll
        for (int i = 0; i < 4; i++) {
            int cl = cq * 4 + i;
            float a = zq[(size_t)(ch + cl) * PIX + h * 64 + w];
#pragma unroll
            for (int k = 0; k < KK; k++) {
                int di = k / 7 - 3;
                int dj = k % 7 - 3;
                int row = r + 3 + di;     // 0..7, always staged
                float v = s2[(row * CCH + cl) * LW + 4 + w + dj];
                acc[k] = fmaf(a, v, acc[k]);
            }
        }
        __syncthreads();
    }

    // cross-cq reduction in LDS (stage buffer dead now)
    float* red = smem;   // [r][buf][k][w] = [2][2][49][64]
#define RED(rr, bb, kk_) red[(((rr) * 2 + (bb)) * KK + (kk_)) * 64 + w]
    if (cq == 1) {
#pragma unroll
        for (int k = 0; k < KK; k++) RED(r, 0, k) = acc[k];
    }
    if (cq == 3) {
#pragma unroll
        for (int k = 0; k < KK; k++) RED(r, 1, k) = acc[k];
    }
    __syncthreads();
    if (cq == 0) {
#pragma unroll
        for (int k = 0; k < KK; k++) acc[k] += RED(r, 0, k);
    }
    if (cq == 2) {
#pragma unroll
        for (int k = 0; k < KK; k++) acc[k] += RED(r, 1, k);
    }
    __syncthreads();
    if (cq == 2) {
#pragma unroll
        for (int k = 0; k < KK; k++) RED(r, 0, k) = acc[k];
    }
    __syncthreads();
    if (cq == 0) {
#pragma unroll
        for (int k = 0; k < KK; k++) acc[k] += RED(r, 0, k);
        float m = acc[0];
#pragma unroll
        for (int k = 1; k < KK; k++) m = fmaxf(m, acc[k]);
        float s = 0.f;
#pragma unroll
        for (int k = 0; k < KK; k++) {
            float e = __expf(acc[k] - m);
            acc[k] = e;
            s += e;
        }
        float inv = 1.f / s;
        float* ap = attn + ((size_t)(n * 64 + h) * KK) * 64 + w;
#pragma unroll
        for (int k = 0; k < KK; k++) ap[(size_t)k * 64] = acc[k] * inv;
    }
#undef RED
}

// ---------------------------------------------------------------------------
// K3: u[c](p) = sum_k attn[k](p) * x[c](p+dk)   (values = raw x)
// ---------------------------------------------------------------------------
__global__ __launch_bounds__(512) void pv2(const float* __restrict__ x,
                                           const float* __restrict__ attn,
                                           float* __restrict__ u) {
    __shared__ float s3[SROWS * CCH * LW];

    int bid = blockIdx.x;
    int hp  = bid & 31;
    int n   = bid >> 5;
    int h0  = hp * 2;

    int tid = threadIdx.x;
    int wid = tid >> 6;
    int w   = tid & 63;
    int r   = wid & 1;
    int cq  = wid >> 1;
    int h   = h0 + r;

    const float* xv = x + (size_t)n * C * PIX;
    const float* ap = attn + ((size_t)(n * 64 + h) * KK) * 64 + w;

    float ar[KK];
#pragma unroll
    for (int k = 0; k < KK; k++) ar[k] = ap[(size_t)k * 64];

    for (int i = tid; i < SROWS * CCH * LW; i += 512) s3[i] = 0.f;
    __syncthreads();   // zeros must land before any staging write

    for (int ch = 0; ch < C; ch += CCH) {
#pragma unroll
        for (int i = 0; i < 4; i++) {
            int q   = tid + i * 512;
            int w4  = q & 15;
            int c   = (q >> 4) & 15;
            int row = q >> 8;
            int hh  = h0 - 3 + row;
            float4 v = make_float4(0.f, 0.f, 0.f, 0.f);
            if ((unsigned)hh < 64u)
                v = *(const float4*)&xv[(size_t)(ch + c) * PIX + hh * 64 + w4 * 4];
            *(float4*)&s3[(row * CCH + c) * LW + 4 + w4 * 4] = v;
        }
        __syncthreads();

#pragma unroll
        for (int i = 0; i < 4; i++) {
            int cl = cq * 4 + i;
            int gc = ch + cl;
            float acc = 0.f;
#pragma unroll
            for (int k = 0; k < KK; k++) {
                int di = k / 7 - 3;
                int dj = k % 7 - 3;
                int row = r + 3 + di;
                float v = s3[(row * CCH + cl) * LW + 4 + w + dj];
                acc = fmaf(ar[k], v, acc);
            }
            u[(size_t)(n * C + gc) * PIX + h * 64 + w] = acc;
        }
        __syncthreads();
    }
}

// ---------------------------------------------------------------------------
extern "C" void kernel_launch(void* const* d_in, const int* in_sizes, int n_in,
                              void* d_out, int out_size, void* d_ws, size_t ws_size,
                              hipStream_t stream) {
    const float* x  = (const float*)d_in[0];
    const float* w1 = (const float*)d_in[1];
    const float* w2 = (const float*)d_in[2];
    const float* w3 = (const float*)d_in[3];
    float* wsf = (float*)d_ws;

    prep<<<68, 256, 0, stream>>>(w1, w2, w3, wsf + M_OFF, wsf + WT3_OFF);
    convk<<<512, 256, 0, stream>>>(wsf + M_OFF, x, wsf + Z_OFF);          // z = M^T x
    simsoft2<<<256, 512, 0, stream>>>(wsf + Z_OFF, x, wsf + ATT_OFF);
    pv2<<<256, 512, 0, stream>>>(x, wsf + ATT_OFF, wsf + U_OFF);          // u = PV(x)
    convk<<<512, 256, 0, stream>>>(wsf + WT3_OFF, wsf + U_OFF, (float*)d_out); // out = W3 u
}